// Round 1
// 97.705 us; speedup vs baseline: 1.0064x; 1.0064x over previous
//
#include <hip/hip_runtime.h>
#include <math.h>

// EfficientByteMUL: fused decode -> tiny-MLP (collapsed to 1 output scalar) -> patch+copy.
//
// Layout facts (from reference):
//   x_bd [8,8192,128] fp32, 65536 tokens of 128 floats (= 32 float4 per row).
//   mask      = x[0]>=0.5 && x[1]>=0.5
//   a_lo=argmax x[16:32], a_hi=argmax x[32:48], b_lo=argmax x[48:64], b_hi=argmax x[64:80]
//   byte_a = a_lo | a_hi<<4 ; byte_b = b_lo | b_hi<<4
//   h_j = relu(byte_a*W1[0,j] + byte_b*W1[1,j] + W1[29,j] + b1[j])      (j=0..255)
//   y   = sum_j h_j * W2[j,40] + b2[40]
//   res = ((int)rint(y)) & 255
//   out = x_bd; out[80 + (res&15)] += 2*mask; out[96 + (res>>4)&15] += 2*mask
//
// One half-wave (32 lanes) per token: lane c holds float4 elements 4c..4c+3,
// so each full-wave load/store is a coalesced 1KB segment.
//
// This revision vs previous:
//  (a) software-pipelined next-token load (2 loads in flight per half-wave,
//      hides the serial shuffle/fp64 chain under HBM latency)
//  (b) wave-uniform fast path: P(mask)=0.25 -> 56% of wave iterations have no
//      masked token in EITHER half; those now do load -> mask shfl -> store,
//      skipping argmax butterflies, MLP, fp64 reduce and patch compares.

#define HID 256

__global__ __launch_bounds__(256) void ebm_fused_kernel(
    const float* __restrict__ x,    // [tokens,128]
    const float* __restrict__ W1,   // [64,256] row-major
    const float* __restrict__ b1,   // [256]
    const float* __restrict__ W2,   // [256,64] row-major
    const float* __restrict__ b2,   // [64]
    float* __restrict__ out,        // [tokens,128]
    int tokens)
{
    const int tid = threadIdx.x;
    const int c = tid & 31;          // lane within half-wave == float4 column of row

    // ---- per-lane weight slices, j = c + 32*k (coalesced loads, register-resident) ----
    float r0[8], r1[8], r29[8], rb1[8], w2c[8];
    #pragma unroll
    for (int k = 0; k < 8; ++k) {
        const int j = c + 32 * k;
        r0[k]  = W1[j];              // W1[0, j]
        r1[k]  = W1[HID + j];        // W1[1, j]
        r29[k] = W1[29 * HID + j];   // W1[29, j]
        rb1[k] = b1[j];
        w2c[k] = W2[j * 64 + 40];    // W2[j, 40]
    }
    const float b2v = b2[40];

    const int nHW = (gridDim.x * blockDim.x) >> 5;       // total half-waves
    const int hw0 = (blockIdx.x * blockDim.x + tid) >> 5;

    const float4* __restrict__ in4  = (const float4*)x;
    float4*       __restrict__ out4 = (float4*)out;

    // ---- software pipeline: keep next iteration's load in flight ----
    float4 v = make_float4(0.f, 0.f, 0.f, 0.f);
    int tok = hw0;
    if (tok < tokens) v = in4[tok * 32 + c];

    while (tok < tokens) {
        const int tnext = tok + nHW;
        float4 vn = make_float4(0.f, 0.f, 0.f, 0.f);
        if (tnext < tokens) vn = in4[tnext * 32 + c];    // issued before the chain below

        // ---- mask (elements 0,1 live in lane c==0 of each half-wave) ----
        const int valid = (v.x >= 0.5f) && (v.y >= 0.5f);
        const int mval = __shfl(valid, 0, 32);

        // ---- wave-uniform fast path: no masked token in either half (56%) ----
        if (__ballot(mval) == 0ull) {
            out4[tok * 32 + c] = v;
            v = vn;
            tok = tnext;
            continue;
        }

        // ---- local argmax over this lane's 4 elements ----
        // fields: lanes 4..7 -> a_lo, 8..11 -> a_hi, 12..15 -> b_lo, 16..19 -> b_hi
        // field-local index of this lane's first element: (c&3)*4
        const int fi = (c & 3) << 2;
        float m = v.x; int g = fi;
        if (v.y > m) { m = v.y; g = fi + 1; }
        if (v.z > m) { m = v.z; g = fi + 2; }
        if (v.w > m) { m = v.w; g = fi + 3; }
        // butterfly across the 4-lane group; tie -> lowest index (matches jnp.argmax)
        {
            float om = __shfl_xor(m, 1, 32);
            int   og = __shfl_xor(g, 1, 32);
            if (om > m || (om == m && og < g)) { m = om; g = og; }
            om = __shfl_xor(m, 2, 32);
            og = __shfl_xor(g, 2, 32);
            if (om > m || (om == m && og < g)) { m = om; g = og; }
        }
        const int a_lo = __shfl(g, 4, 32);
        const int a_hi = __shfl(g, 8, 32);
        const int b_lo = __shfl(g, 12, 32);
        const int b_hi = __shfl(g, 16, 32);

        // ---- tiny MLP collapsed to one scalar (fp64 accumulate for exact rint) ----
        const float af = (float)(a_lo | (a_hi << 4));
        const float bf = (float)(b_lo | (b_hi << 4));
        double acc = 0.0;
        #pragma unroll
        for (int k = 0; k < 8; ++k) {
            float t = af * r0[k];
            t += bf * r1[k];
            t += r29[k];
            t += rb1[k];
            t = fmaxf(t, 0.0f);                  // relu
            acc = fma((double)t, (double)w2c[k], acc);
        }
        // butterfly sum across the 32 lanes of this half-wave
        acc += __shfl_xor(acc, 16, 32);
        acc += __shfl_xor(acc,  8, 32);
        acc += __shfl_xor(acc,  4, 32);
        acc += __shfl_xor(acc,  2, 32);
        acc += __shfl_xor(acc,  1, 32);
        const double y = acc + (double)b2v;
        const int res = ((int)rint(y)) & 255;    // rint = half-to-even, matches np.round

        // ---- patch + store ----
        const int t_lo = 80 + (res & 15);
        const int t_hi = 96 + ((res >> 4) & 15);
        const float addv = mval ? 2.0f : 0.0f;
        const int e0 = c << 2;                   // element index of v.x
        v.x += (e0     == t_lo || e0     == t_hi) ? addv : 0.0f;
        v.y += (e0 + 1 == t_lo || e0 + 1 == t_hi) ? addv : 0.0f;
        v.z += (e0 + 2 == t_lo || e0 + 2 == t_hi) ? addv : 0.0f;
        v.w += (e0 + 3 == t_lo || e0 + 3 == t_hi) ? addv : 0.0f;

        out4[tok * 32 + c] = v;

        v = vn;
        tok = tnext;
    }
}

extern "C" void kernel_launch(void* const* d_in, const int* in_sizes, int n_in,
                              void* d_out, int out_size, void* d_ws, size_t ws_size,
                              hipStream_t stream) {
    const float* x  = (const float*)d_in[0];
    const float* W1 = (const float*)d_in[1];
    const float* b1 = (const float*)d_in[2];
    const float* W2 = (const float*)d_in[3];
    const float* b2 = (const float*)d_in[4];
    float* out = (float*)d_out;

    const int tokens = in_sizes[0] / 128;   // 8*8192 = 65536

    const int block = 256;                  // 8 half-waves per block
    const int grid  = 2048;                 // 16384 half-waves -> 4 tokens each
    ebm_fused_kernel<<<grid, block, 0, stream>>>(x, W1, b1, W2, b2, out, tokens);
}